// Round 7
// baseline (181.683 us; speedup 1.0000x reference)
//
#include <hip/hip_runtime.h>

// Problem constants (match reference file)
constexpr int Dv = 160, Hv = 192, Wv = 160;
constexpr int NN = Dv * Hv * Wv;  // 4,915,200 voxels

// Round 7: z-marching ring pipeline (T3/T4/T14: counted vmcnt, stage-ahead,
// never drain to 0). Rounds 0-6 showed achieved residency is an equilibrium
// (~3 blocks/CU regardless of caps) because each block's life is dominated
// by its own stage->vmcnt(0)->barrier drain; combined traffic plateaus at
// ~3.0 TB/s with every pipe <40% busy. Here each block marches 16 z-slices
// in 4 steps, staging group s+2 and prefetching flow2(s+1) BEFORE computing
// step s, gated by counted s_waitcnt vmcnt(N) -- loads stay in flight
// across barriers for the whole block lifetime.
constexpr int TW = 32, TH = 8, TDS = 4;   // per-step slab 32 x 8 x 4
constexpr int NSTEP = 4;                  // z-chunk = 16 slices per block
// src support plane: x halo [-4,+4) (SX=40, 16B-aligned), y rows [h-2,h+2]
// per voxel -> 12 rows (SY=12). z support per step s (slices a..a+3):
// planes [a-2, a+6] (9), grouped in 4-plane groups, 4-slot ring.
constexpr int SX = 40, SY = 12;
constexpr int PLF = SX * SY;              // 480 floats per plane
constexpr int GRF = PLF * 4;              // 1920 floats per group
constexpr int GRSEG = GRF / 4;            // 480 16B segments per group
constexpr int LDSF = 4 * GRF;             // ring: 7680 floats = 30720 B

#define WAITV(n) asm volatile("s_waitcnt vmcnt(" #n ")" ::: "memory")

// Stage one 4-plane group (absolute group index k -> ring slot k&3).
// Exactly 2 lds-DMA ops per wave (2nd prefix-masked) -> uniform per-wave
// vmcnt contribution; lds addresses are lane-linear (m104 requirement).
__device__ __forceinline__ void stage_group(const float* __restrict__ src,
                                            float* lds, int k, int bxo, int byo) {
  const int tid = threadIdx.x;
  float* base = lds + (k & 3) * GRF;
  const int zb = k * 4;
#pragma unroll
  for (int i = 0; i < 2; ++i) {
    const int t = tid + i * 256;
    if (t < GRSEG) {  // i=0: all lanes; i=1: prefix of each wave
      int p = t / 120;                  // plane in group
      int q = t - p * 120;
      int ty = q / 10;                  // row in plane (10 segs/row)
      int tx4 = (q - ty * 10) * 4;
      int gz = min(max(zb + p, 0), Dv - 1);
      int gy = min(max(byo + ty, 0), Hv - 1);
      int gx = min(max(bxo + tx4, 0), Wv - 4);
      int g = (gz * Hv + gy) * Wv + gx;  // 16B-aligned
      __builtin_amdgcn_global_load_lds(
          (const __attribute__((address_space(1))) void*)(src + g),
          (__attribute__((address_space(3))) void*)(base + t * 4), 16, 0, 0);
    }
  }
}

// Trilinear sample of 3-channel flow1 at quirk-unnormalized coords:
// in-bounds only near the (0,0,0) corner, so execz-skipped for essentially
// every wave. (Its rare loads are OLDER than any gated stage group at the
// next WAITV, so they never break the counted-vmcnt discipline.)
__device__ __forceinline__ void tri3_rare(const float* __restrict__ v,
                                          float gx, float gy, float gz,
                                          float& o0, float& o1, float& o2) {
  o0 = 0.0f; o1 = 0.0f; o2 = 0.0f;
  float ix = ((gx + 1.0f) * (float)Wv - 1.0f) * 0.5f;
  float iy = ((gy + 1.0f) * (float)Hv - 1.0f) * 0.5f;
  float iz = ((gz + 1.0f) * (float)Dv - 1.0f) * 0.5f;
  float fx = floorf(ix), fy = floorf(iy), fz = floorf(iz);
  int x0 = (int)fx, y0 = (int)fy, z0 = (int)fz;
  if (x0 < -1 || x0 >= Wv || y0 < -1 || y0 >= Hv || z0 < -1 || z0 >= Dv)
    return;
  float wx = ix - fx, wy = iy - fy, wz = iz - fz;
#pragma unroll
  for (int c = 0; c < 8; ++c) {
    const int dz = (c >> 2) & 1, dy = (c >> 1) & 1, dx = c & 1;
    int zi = z0 + dz, yi = y0 + dy, xi = x0 + dx;
    if ((unsigned)zi < (unsigned)Dv && (unsigned)yi < (unsigned)Hv &&
        (unsigned)xi < (unsigned)Wv) {
      float wgt = (dz ? wz : 1.0f - wz) * (dy ? wy : 1.0f - wy) *
                  (dx ? wx : 1.0f - wx);
      int lin = (zi * Hv + yi) * Wv + xi;
      o0 += wgt * v[lin];
      o1 += wgt * v[NN + lin];
      o2 += wgt * v[2 * NN + lin];
    }
  }
}

__global__ __launch_bounds__(256)
void st_pipe_kernel(const float* __restrict__ src,
                    const float* __restrict__ flow1,
                    const float* __restrict__ flow2,
                    const float* __restrict__ rfp,
                    float* __restrict__ out) {
  __shared__ float tile[LDSF];

  const int tid = threadIdx.x;
  const float rf = rfp[0];  // scalar; issued before all gated loads

  // XCD-bijective swizzle (1200 = 8 x 150): each XCD gets a contiguous
  // 150-block chunk = ~1.25 z-slabs -> src halo reuse stays in its L2.
  const int bid = (int)blockIdx.x;
  const int swz = (bid & 7) * 150 + (bid >> 3);
  const int bx = swz % 5;
  const int t1 = swz / 5;
  const int by = t1 % 24;
  const int bz = t1 / 24;

  const int bx0 = bx * TW, by0 = by * TH;
  const int zbase = bz * (TDS * NSTEP);   // 16-slice chunk
  const int k0 = bz * NSTEP;              // first compute group index
  const int bxo = bx0 - 4, byo = by0 - 2;

  // ---- prologue: stage groups P(-1), P(0), P(1)  (6 lds-DMA ops/wave) ----
  stage_group(src, tile, k0 - 1, bxo, byo);
  stage_group(src, tile, k0,     bxo, byo);
  stage_group(src, tile, k0 + 1, bxo, byo);

  // thread voxel geometry: 8 x-groups x 8 y x 4 z-slices, 1 float4/step
  const int lx = tid & 7, ly = (tid >> 3) & 7, lz = tid >> 6;
  const int w0 = bx0 + lx * 4;
  const int h = by0 + ly;
  const int idx0 = ((zbase + lz) * Hv + h) * Wv + w0;  // 16B-aligned
  constexpr int ZSTRIDE = TDS * Hv * Wv;

  // flow2 for step 0 (3 dwordx4 ops/wave)
  float4 f2d[2], f2h[2], f2w[2];
  f2d[0] = *(const float4*)(flow2 + idx0);
  f2h[0] = *(const float4*)(flow2 + NN + idx0);
  f2w[0] = *(const float4*)(flow2 + 2 * NN + idx0);

  const float hf = (float)h;
  constexpr float KX = (float)Wv / (float)(Wv - 1);
  constexpr float KY = (float)Hv / (float)(Hv - 1);
  constexpr float KZ = (float)Dv / (float)(Dv - 1);

#pragma unroll
  for (int s = 0; s < NSTEP; ++s) {
    const int cur = s & 1, nxt = cur ^ 1;

    // ---- stage-ahead: group P(s+2) + flow2(s+1), BEFORE computing s ----
    if (s + 2 <= NSTEP)
      stage_group(src, tile, k0 + 2 + s, bxo, byo);     // 2 ops
    if (s + 1 < NSTEP) {
      const int idxn = idx0 + (s + 1) * ZSTRIDE;
      f2d[nxt] = *(const float4*)(flow2 + idxn);         // 3 ops
      f2h[nxt] = *(const float4*)(flow2 + NN + idxn);
      f2w[nxt] = *(const float4*)(flow2 + 2 * NN + idxn);
    }

    // counted wait: guarantee stage(P(s+1)) complete, leave the
    // guaranteed-younger ops in flight:
    //   s=0: stage(P2)2 + f2(1)3            = 5
    //   s=1,2: stores(s-1)4 + stage2 + f2 3 = 9
    //   s=3: stores(2)4                     = 4
    if (s == 0)            WAITV(5);
    else if (s == NSTEP-1) WAITV(4);
    else                   WAITV(9);
    __builtin_amdgcn_sched_barrier(0);
    __builtin_amdgcn_s_barrier();   // all waves' stage(P(s+1)) done

    // ---- compute step s: slices a..a+3 from ring groups s-1,s,s+1 ----
    const int a = zbase + TDS * s;
    const int d = a + lz;
    const float df = (float)d;
    const int idx = idx0 + s * ZSTRIDE;

    float4 def, ofd4, ofh4, ofw4;
#pragma unroll
    for (int j = 0; j < 4; ++j) {
      const float wf = (float)(w0 + j);
      const float f2dv = (&f2d[cur].x)[j];
      const float f2hv = (&f2h[cur].x)[j];
      const float f2wv = (&f2w[cur].x)[j];

      float a0, a1, a2;  // flow1 warped (d,h,w channels)
      tri3_rare(flow1, wf + rf * f2wv, hf + rf * f2hv, df + rf * f2dv,
                a0, a1, a2);

      float of_d = a0 + f2dv;
      float of_h = a1 + f2hv;
      float of_w = a2 + f2wv;
      (&ofd4.x)[j] = of_d;
      (&ofh4.x)[j] = of_h;
      (&ofw4.x)[j] = of_w;

      float ix = (wf + rf * of_w) * KX - 0.5f;
      float iy = (hf + rf * of_h) * KY - 0.5f;
      float iz = (df + rf * of_d) * KZ - 0.5f;

      float fx = floorf(ix), fy = floorf(iy), fz = floorf(iz);
      float wx = ix - fx, wy = iy - fy, wz = iz - fz;
      int x0 = (int)fx, y0 = (int)fy, z0 = (int)fz;

      float wx0 = ((unsigned)x0 < (unsigned)Wv) ? (1.0f - wx) : 0.0f;
      float wx1 = ((unsigned)(x0 + 1) < (unsigned)Wv) ? wx : 0.0f;
      float wy0 = ((unsigned)y0 < (unsigned)Hv) ? (1.0f - wy) : 0.0f;
      float wy1 = ((unsigned)(y0 + 1) < (unsigned)Hv) ? wy : 0.0f;
      float wz0 = ((unsigned)z0 < (unsigned)Dv) ? (1.0f - wz) : 0.0f;
      float wz1 = ((unsigned)(z0 + 1) < (unsigned)Dv) ? wz : 0.0f;

      int txi = x0 - bxo, tyi = y0 - byo, tzi = z0 - (a - 2);
      bool fast = ((unsigned)txi <= (unsigned)(SX - 2)) &
                  ((unsigned)tyi <= (unsigned)(SY - 2)) &
                  ((unsigned)tzi <= 7u);   // z0 in [a-2, a+5]

      float v000, v001, v010, v011, v100, v101, v110, v111;
      if (fast) {
        int yx = tyi * SX + txi;
        int z1 = z0 + 1;
        int b0 = ((z0 >> 2) & 3) * GRF + (z0 & 3) * PLF + yx;
        int b1 = ((z1 >> 2) & 3) * GRF + (z1 & 3) * PLF + yx;
        v000 = tile[b0];      v001 = tile[b0 + 1];
        v010 = tile[b0 + SX]; v011 = tile[b0 + SX + 1];
        v100 = tile[b1];      v101 = tile[b1 + 1];
        v110 = tile[b1 + SX]; v111 = tile[b1 + SX + 1];
      } else {
        // rare: out-of-halo -> clamped global gather
        int xa0 = min(max(x0, 0), Wv - 1), xa1 = min(max(x0 + 1, 0), Wv - 1);
        int ya0 = min(max(y0, 0), Hv - 1), ya1 = min(max(y0 + 1, 0), Hv - 1);
        int za0 = min(max(z0, 0), Dv - 1), za1 = min(max(z0 + 1, 0), Dv - 1);
        int r00 = (za0 * Hv + ya0) * Wv;
        int r01 = (za0 * Hv + ya1) * Wv;
        int r10 = (za1 * Hv + ya0) * Wv;
        int r11 = (za1 * Hv + ya1) * Wv;
        v000 = src[r00 + xa0]; v001 = src[r00 + xa1];
        v010 = src[r01 + xa0]; v011 = src[r01 + xa1];
        v100 = src[r10 + xa0]; v101 = src[r10 + xa1];
        v110 = src[r11 + xa0]; v111 = src[r11 + xa1];
      }

      float c00 = v000 * wx0 + v001 * wx1;
      float c01 = v010 * wx0 + v011 * wx1;
      float c10 = v100 * wx0 + v101 * wx1;
      float c11 = v110 * wx0 + v111 * wx1;
      float c0 = c00 * wy0 + c01 * wy1;
      float c1 = c10 * wy0 + c11 * wy1;
      (&def.x)[j] = c0 * wz0 + c1 * wz1;
    }

    // ---- vectorized stores (4 dwordx4/wave; left in flight, counted) ----
    *(float4*)(out + idx) = def;
    *(float4*)(out + NN + idx) = ofd4;
    *(float4*)(out + 2 * NN + idx) = ofh4;
    *(float4*)(out + 3 * NN + idx) = ofw4;

    // ring WAR gate: all waves done reading slot (s+2)&3's old contents
    // before iter s+1 stages into it
    __builtin_amdgcn_s_barrier();
    __builtin_amdgcn_sched_barrier(0);
  }
}

extern "C" void kernel_launch(void* const* d_in, const int* in_sizes, int n_in,
                              void* d_out, int out_size, void* d_ws, size_t ws_size,
                              hipStream_t stream) {
  const float* src   = (const float*)d_in[0];
  const float* flow1 = (const float*)d_in[1];
  const float* flow2 = (const float*)d_in[2];
  const float* rfp   = (const float*)d_in[3];
  float* out = (float*)d_out;

  // 5 x 24 xy-tiles x 10 z-chunks = 1200 blocks (1D for swizzle)
  hipLaunchKernelGGL(st_pipe_kernel, dim3(1200), dim3(256), 0, stream,
                     src, flow1, flow2, rfp, out);
}